// Round 1
// baseline (106.709 us; speedup 1.0000x reference)
//
#include <hip/hip_runtime.h>
#include <math.h>

#define NUM_CLASSES 16
#define MARGIN_F 0.3f
#define EPS_F 1e-8f

// ws layout (as float*):
//   [0..255]   : D16 distance matrix (row-major, D16[c1*16+c2])
//   [256..271] : first_idx (as int, via reinterpret)
//   [272..287] : present flags (1.0f / 0.0f)
//   [288..290] : accumulators {rank_sum, per_sum, valid_cnt}

__global__ __launch_bounds__(256) void k_first(const int* __restrict__ targets, int B,
                                               int* __restrict__ wsFirst,
                                               float* __restrict__ wsPresent,
                                               float* __restrict__ wsAcc) {
    __shared__ int fi[NUM_CLASSES];
    int t = threadIdx.x;
    if (t < NUM_CLASSES) fi[t] = 0x7fffffff;
    __syncthreads();
    for (int j = t; j < B; j += 256) {
        int c = targets[j];
        if (c >= 0 && c < NUM_CLASSES) atomicMin(&fi[c], j);
    }
    __syncthreads();
    if (t < NUM_CLASSES) {
        int v = fi[t];
        int pres = (v != 0x7fffffff);
        wsPresent[t] = pres ? 1.0f : 0.0f;
        wsFirst[t] = pres ? v : 0;   // argmax over all-False returns 0
    }
    if (t < 3) wsAcc[t] = 0.0f;      // ws is poisoned 0xAA each call — must zero
}

// One wave per (c1,c2) pair: coalesced reads of the two rows, shuffle-reduce.
__global__ __launch_bounds__(64) void k_dist(const float* __restrict__ x, int Dm,
                                             const int* __restrict__ wsFirst,
                                             float* __restrict__ D16) {
    int pair = blockIdx.x;
    int c1 = pair >> 4, c2 = pair & 15;
    const float* __restrict__ x1 = x + (long)wsFirst[c1] * Dm;
    const float* __restrict__ x2 = x + (long)wsFirst[c2] * Dm;
    int l = threadIdx.x;
    float dot = 0.f, s1 = 0.f, s2 = 0.f;
    for (int k = l; k < Dm; k += 64) {
        float a = x1[k], b = x2[k];
        dot = fmaf(a, b, dot);
        s1  = fmaf(a, a, s1);
        s2  = fmaf(b, b, s2);
    }
    #pragma unroll
    for (int off = 32; off > 0; off >>= 1) {
        dot += __shfl_down(dot, off);
        s1  += __shfl_down(s1, off);
        s2  += __shfl_down(s2, off);
    }
    if (l == 0) {
        float d2 = s1 + s2 - 2.0f * dot;   // c1==c2 -> exactly 0 in fp32
        D16[pair] = sqrtf(fmaxf(d2, 1e-12f));
    }
}

__global__ __launch_bounds__(256) void k_reduce(const int* __restrict__ ua, int T,
                                                const float* __restrict__ D16,
                                                const float* __restrict__ wsPresent,
                                                float* __restrict__ wsAcc) {
    __shared__ float sD[256];
    __shared__ float sP[NUM_CLASSES];
    __shared__ float sRed[4][3];
    int t = threadIdx.x;
    sD[t] = D16[t];
    if (t < NUM_CLASSES) sP[t] = wsPresent[t];
    __syncthreads();

    float r = 0.f, pp = 0.f, cnt = 0.f;
    for (int i = blockIdx.x * blockDim.x + t; i < T; i += gridDim.x * blockDim.x) {
        int a = ua[3 * i + 0];
        int b = ua[3 * i + 1];
        int c = ua[3 * i + 2];
        float valid = sP[a] * sP[b] * sP[c];
        float dap = sD[(a << 4) | b];
        float dan = sD[(a << 4) | c];
        float rank = fmaxf(dap - dan + MARGIN_F, 0.0f);
        float sap = 1.0f / (dap + 1.0f);
        float san = 1.0f / (dan + 1.0f);
        float per = -logf(sap / (sap + san) + EPS_F);
        r   += valid * rank;
        pp  += valid * per;
        cnt += valid;
    }
    #pragma unroll
    for (int off = 32; off > 0; off >>= 1) {
        r   += __shfl_down(r, off);
        pp  += __shfl_down(pp, off);
        cnt += __shfl_down(cnt, off);
    }
    int wave = t >> 6, lane = t & 63;
    if (lane == 0) { sRed[wave][0] = r; sRed[wave][1] = pp; sRed[wave][2] = cnt; }
    __syncthreads();
    if (t == 0) {
        float R = 0.f, P = 0.f, C = 0.f;
        #pragma unroll
        for (int w = 0; w < 4; ++w) { R += sRed[w][0]; P += sRed[w][1]; C += sRed[w][2]; }
        atomicAdd(&wsAcc[0], R);
        atomicAdd(&wsAcc[1], P);
        atomicAdd(&wsAcc[2], C);
    }
}

__global__ void k_final(const float* __restrict__ wsAcc, float* __restrict__ out) {
    float nv = fmaxf(wsAcc[2], 1.0f);
    float lh = wsAcc[0] / nv;
    float lp = wsAcc[1] / nv;
    out[0] = lh + lp;
    out[1] = lh;
    out[2] = lp;
}

extern "C" void kernel_launch(void* const* d_in, const int* in_sizes, int n_in,
                              void* d_out, int out_size, void* d_ws, size_t ws_size,
                              hipStream_t stream) {
    // setup_inputs order:
    // 0: preds_mat (unused)  1: preds_sub (unused)  2: inputs (B,D) f32
    // 3: targets_mat (B,) int  4: targets_sub (unused)  5: user_answers (T,3) int
    const float* x       = (const float*)d_in[2];
    const int*   targets = (const int*)d_in[3];
    const int*   ua      = (const int*)d_in[5];
    float* out = (float*)d_out;

    int B  = in_sizes[3];
    int Dm = in_sizes[2] / B;
    int T  = in_sizes[5] / 3;

    float* ws      = (float*)d_ws;
    float* D16     = ws;            // 256 floats
    int*   wsFirst = (int*)(ws + 256);   // 16 ints
    float* wsPres  = ws + 272;      // 16 floats
    float* wsAcc   = ws + 288;      // 3 floats

    k_first<<<1, 256, 0, stream>>>(targets, B, wsFirst, wsPres, wsAcc);
    k_dist<<<256, 64, 0, stream>>>(x, Dm, wsFirst, D16);
    k_reduce<<<512, 256, 0, stream>>>(ua, T, D16, wsPres, wsAcc);
    k_final<<<1, 1, 0, stream>>>(wsAcc, out);
}